// Round 2
// baseline (497.613 us; speedup 1.0000x reference)
//
#include <hip/hip_runtime.h>

typedef short short8 __attribute__((ext_vector_type(8)));
typedef float f32x4 __attribute__((ext_vector_type(4)));

#define B_ROWS 16384
#define SCALE 1.4285714285714286f   // rounds to f32 1.42857146..., same as np's f32 cast of 1/0.7

__device__ __forceinline__ float bf2f(unsigned short u) {
    return __uint_as_float(((unsigned)u) << 16);
}
__device__ __forceinline__ unsigned short f2bf(float f) {
    unsigned u = __float_as_uint(f);
    u += 0x7fffu + ((u >> 16) & 1u);   // RNE
    return (unsigned short)(u >> 16);
}

__device__ __forceinline__ void gl_lds16(const void* g, void* l) {
    __builtin_amdgcn_global_load_lds(
        (const __attribute__((address_space(1))) unsigned int*)g,
        (__attribute__((address_space(3))) unsigned int*)l, 16, 0, 0);
}

__device__ __forceinline__ float wave_max(float v) {
    #pragma unroll
    for (int m = 1; m < 64; m <<= 1) v = fmaxf(v, __shfl_xor(v, m, 64));
    return v;
}
__device__ __forceinline__ float wave_sum(float v) {
    #pragma unroll
    for (int m = 1; m < 64; m <<= 1) v += __shfl_xor(v, m, 64);
    return v;
}

// ---- prep: W1 f32 (4096x128) -> transposed bf16 hi/lo splits (128x4096) ----
__global__ void k_prep(const float* __restrict__ w1,
                       unsigned short* __restrict__ w1h,
                       unsigned short* __restrict__ w1l) {
    int tid = blockIdx.x * 256 + threadIdx.x;     // 524288 total
    int n = tid >> 12, k = tid & 4095;
    float v = w1[k * 128 + n];
    unsigned short hi = f2bf(v);
    w1h[tid] = hi;
    w1l[tid] = f2bf(v - bf2f(hi));
}

// ---- GEMM1: h = relu(x @ W1 + b1), split-bf16 3-pass MFMA, f32 in/out -----
// tile M=32, N=128, BK=64; grid 512; 4 waves x (32x32 subtile)
__global__ __launch_bounds__(256) void k_gemm(const float* __restrict__ x,
                                              const unsigned short* __restrict__ w1h,
                                              const unsigned short* __restrict__ w1l,
                                              const float* __restrict__ b1,
                                              float* __restrict__ hout) {
    __shared__ unsigned short sAh[2][32 * 64], sAl[2][32 * 64];   // 8 KB each
    __shared__ unsigned short sBh[2][128 * 64], sBl[2][128 * 64]; // 32 KB each
    const int t = threadIdx.x;
    const int w = t >> 6, lane = t & 63;
    const int l15 = lane & 15, l4 = lane >> 4;
    const int rowBase = blockIdx.x << 5;

    f32x4 acc[2][2];
    #pragma unroll
    for (int i = 0; i < 2; ++i)
        #pragma unroll
        for (int j = 0; j < 2; ++j) {
            f32x4 z = {0.f, 0.f, 0.f, 0.f};
            acc[i][j] = z;
        }

    const int am = t >> 3, as = t & 7;            // A staging: row, 8-float seg
    const int apc = as ^ (am & 7);                // swizzled chunk col

    auto stage = [&](int buf, int k0) {
        // B tiles: async global->LDS, 16B chunks, XOR swizzle on source
        #pragma unroll
        for (int j = 0; j < 4; ++j) {
            int c = j * 256 + t;                  // 0..1023
            int n = c >> 3;
            int cl = (c & 7) ^ (n & 7);
            const size_t go = (size_t)n * 4096 + k0 + (cl << 3);
            gl_lds16(w1h + go, &sBh[buf][c << 3]);
            gl_lds16(w1l + go, &sBl[buf][c << 3]);
        }
        // A tile: load f32, split to bf16 hi/lo, ds_write_b128
        const float* src = x + ((size_t)(rowBase + am) << 12) + k0 + (as << 3);
        float4 a0 = *(const float4*)src;
        float4 a1 = *(const float4*)(src + 4);
        float av[8] = {a0.x, a0.y, a0.z, a0.w, a1.x, a1.y, a1.z, a1.w};
        short8 H, L;
        #pragma unroll
        for (int i = 0; i < 8; ++i) {
            unsigned short hi = f2bf(av[i]);
            H[i] = (short)hi;
            L[i] = (short)f2bf(av[i] - bf2f(hi));
        }
        *(short8*)&sAh[buf][((am << 3) + apc) << 3] = H;
        *(short8*)&sAl[buf][((am << 3) + apc) << 3] = L;
    };

    stage(0, 0);
    __syncthreads();
    for (int it = 0; it < 64; ++it) {
        int buf = it & 1;
        if (it + 1 < 64) stage(buf ^ 1, (it + 1) << 6);
        #pragma unroll
        for (int ks = 0; ks < 2; ++ks) {
            short8 ah[2], al[2], bh[2], bl[2];
            #pragma unroll
            for (int mf = 0; mf < 2; ++mf) {
                int rm = (mf << 4) + l15;
                int pc = ((ks << 2) + l4) ^ (rm & 7);
                ah[mf] = *(const short8*)&sAh[buf][(((rm << 3) + pc)) << 3];
                al[mf] = *(const short8*)&sAl[buf][(((rm << 3) + pc)) << 3];
            }
            #pragma unroll
            for (int nf = 0; nf < 2; ++nf) {
                int rn = (w << 5) + (nf << 4) + l15;
                int pc = ((ks << 2) + l4) ^ (rn & 7);
                bh[nf] = *(const short8*)&sBh[buf][(((rn << 3) + pc)) << 3];
                bl[nf] = *(const short8*)&sBl[buf][(((rn << 3) + pc)) << 3];
            }
            #pragma unroll
            for (int mf = 0; mf < 2; ++mf)
                #pragma unroll
                for (int nf = 0; nf < 2; ++nf) {
                    acc[mf][nf] = __builtin_amdgcn_mfma_f32_16x16x32_bf16(
                        ah[mf], bh[nf], acc[mf][nf], 0, 0, 0);
                    acc[mf][nf] = __builtin_amdgcn_mfma_f32_16x16x32_bf16(
                        ah[mf], bl[nf], acc[mf][nf], 0, 0, 0);
                    acc[mf][nf] = __builtin_amdgcn_mfma_f32_16x16x32_bf16(
                        al[mf], bh[nf], acc[mf][nf], 0, 0, 0);
                }
        }
        __syncthreads();
    }

    // epilogue: C/D layout col=lane&15, row=(lane>>4)*4+reg
    #pragma unroll
    for (int nf = 0; nf < 2; ++nf) {
        int col = (w << 5) + (nf << 4) + l15;
        float bias = b1[col];
        #pragma unroll
        for (int mf = 0; mf < 2; ++mf) {
            int r0 = rowBase + (mf << 4) + (l4 << 2);
            #pragma unroll
            for (int rr = 0; rr < 4; ++rr) {
                float v = acc[mf][nf][rr] + bias;
                hout[(size_t)(r0 + rr) * 128 + col] = v > 0.f ? v : 0.f;
            }
        }
    }
}

// ---- stage 2: masked logits, exact f32 VALU, W2 wave-uniform broadcast ----
// block 640 = 10 waves: (s, e-half); thread = (s, row=lane, eh)
__global__ __launch_bounds__(640) void k_logits(const float* __restrict__ h,
                                                const float* __restrict__ w2,
                                                const float* __restrict__ b2,
                                                const float* __restrict__ m1,
                                                const float* __restrict__ m2,
                                                float* __restrict__ lg) {
    const int t = threadIdx.x;
    const int wave = t >> 6, lane = t & 63;
    const int eh = (wave >= 5) ? 1 : 0;
    const int s = wave - (eh ? 5 : 0);
    const int row = (blockIdx.x << 6) + lane;
    const int ebu = __builtin_amdgcn_readfirstlane(eh << 5);   // wave-uniform

    float acc[32];
    #pragma unroll
    for (int e = 0; e < 32; ++e) acc[e] = 0.f;

    const float* hp = h + (size_t)row * 128;
    const float* m1p = m1 + ((size_t)s * B_ROWS + row) * 128;
    const float* wp = w2 + ebu;

    for (int k = 0; k < 128; k += 4) {
        float4 h4 = *(const float4*)(hp + k);
        float4 mu = *(const float4*)(m1p + k);
        float hd0 = (mu.x >= 0.3f) ? h4.x * SCALE : 0.f;
        float hd1 = (mu.y >= 0.3f) ? h4.y * SCALE : 0.f;
        float hd2 = (mu.z >= 0.3f) ? h4.z * SCALE : 0.f;
        float hd3 = (mu.w >= 0.3f) ? h4.w * SCALE : 0.f;
        const float* wk = wp + (k << 6);
        #pragma unroll
        for (int e = 0; e < 32; ++e) acc[e] += hd0 * wk[e];
        #pragma unroll
        for (int e = 0; e < 32; ++e) acc[e] += hd1 * wk[64 + e];
        #pragma unroll
        for (int e = 0; e < 32; ++e) acc[e] += hd2 * wk[128 + e];
        #pragma unroll
        for (int e = 0; e < 32; ++e) acc[e] += hd3 * wk[192 + e];
    }

    const float* m2p = m2 + ((size_t)s * B_ROWS + row) * 64 + ebu;
    float* op = lg + ((size_t)s * B_ROWS + row) * 64 + ebu;
    #pragma unroll
    for (int e = 0; e < 32; ++e) {
        float lv = acc[e] + b2[ebu + e];
        acc[e] = (m2p[e] >= 0.3f) ? lv * SCALE : 0.f;
    }
    #pragma unroll
    for (int e = 0; e < 32; e += 4) {
        float4 v = make_float4(acc[e], acc[e + 1], acc[e + 2], acc[e + 3]);
        *(float4*)(op + e) = v;
    }
}

// ---- stats: wave per row, lane = expert, register-resident, f32 out ------
__global__ __launch_bounds__(256) void k_stats(const float* __restrict__ lg,
                                               float* __restrict__ out) {
    const int lane = threadIdx.x & 63;
    const int wv = threadIdx.x >> 6;
    const int row = (blockIdx.x << 2) + wv;

    float l[5], p[5];
    #pragma unroll
    for (int s = 0; s < 5; ++s)
        l[s] = lg[((size_t)s * B_ROWS + row) * 64 + lane];

    // np.mean axis=0: sequential sum then divide
    float ml = (((l[0] + l[1]) + l[2]) + l[3] + l[4]);
    ml = ((((l[0] + l[1]) + l[2]) + l[3]) + l[4]) / 5.0f;

    #pragma unroll
    for (int s = 0; s < 5; ++s) {
        float mx = wave_max(l[s]);
        float ev = expf(l[s] - mx);
        float sm = wave_sum(ev);
        p[s] = ev / sm;
    }

    float mx = wave_max(ml);
    float ev = expf(ml - mx);
    float sm = wave_sum(ev);
    float prob = ev / sm;

    // ddof=1 std over 5 samples, two-pass like np
    float mean = ((((p[0] + p[1]) + p[2]) + p[3]) + p[4]) / 5.0f;
    float var = 0.f;
    #pragma unroll
    for (int s = 0; s < 5; ++s) { float d = p[s] - mean; var += d * d; }
    float sd = sqrtf(var * 0.25f);
    float unc = wave_sum(sd) / 64.0f;

    // top-4 via 4x argmax-allreduce; ties -> lowest index (lax.top_k)
    float pv = prob;
    float vv[4]; int vi[4];
    #pragma unroll
    for (int t4 = 0; t4 < 4; ++t4) {
        float bv = pv; int bi = lane;
        #pragma unroll
        for (int m = 1; m < 64; m <<= 1) {
            float ov = __shfl_xor(bv, m, 64);
            int oi = __shfl_xor(bi, m, 64);
            if (ov > bv || (ov == bv && oi < bi)) { bv = ov; bi = oi; }
        }
        vv[t4] = bv; vi[t4] = bi;
        if (lane == bi) pv = -1.f;
    }

    if (lane == 0) {
        bool ug = unc > 0.3f;
        float4 fi = make_float4((float)vi[0], (float)vi[1],
                                ug ? (float)vi[2] : -1.f,
                                ug ? (float)vi[3] : -1.f);
        *(float4*)(out + (size_t)row * 4) = fi;
        float4 fp = make_float4(vv[0], vv[1],
                                ug ? vv[2] : 0.f,
                                ug ? vv[3] : 0.f);
        *(float4*)(out + 65536 + (size_t)row * 4) = fp;
        out[131072 + row] = unc;
    }
}

extern "C" void kernel_launch(void* const* d_in, const int* in_sizes, int n_in,
                              void* d_out, int out_size, void* d_ws, size_t ws_size,
                              hipStream_t stream) {
    const float* x  = (const float*)d_in[0];
    const float* W1 = (const float*)d_in[1];
    const float* b1 = (const float*)d_in[2];
    const float* W2 = (const float*)d_in[3];
    const float* b2 = (const float*)d_in[4];
    const float* m1 = (const float*)d_in[5];
    const float* m2 = (const float*)d_in[6];
    float* out = (float*)d_out;
    char* ws = (char*)d_ws;

    unsigned short* w1h = (unsigned short*)ws;          // 1 MB
    unsigned short* w1l = (unsigned short*)(ws + (1 << 20));  // 1 MB
    float* h  = (float*)(ws + (2 << 20));               // 8 MB  (16384x128 f32)
    float* lg = (float*)(ws + (10 << 20));              // 21 MB (5x16384x64 f32)

    k_prep  <<<2048, 256, 0, stream>>>(W1, w1h, w1l);
    k_gemm  <<<512,  256, 0, stream>>>(x, w1h, w1l, b1, h);
    k_logits<<<256,  640, 0, stream>>>(h, W2, b2, m1, m2, lg);
    k_stats <<<4096, 256, 0, stream>>>(lg, out);
}

// Round 3
// 497.523 us; speedup vs baseline: 1.0002x; 1.0002x over previous
//
#include <hip/hip_runtime.h>

typedef short short8 __attribute__((ext_vector_type(8)));
typedef float f32x4 __attribute__((ext_vector_type(4)));

#define B_ROWS 16384
#define SCALE 1.4285714285714286f   // f32 round of 1/0.7, same as np

__device__ __forceinline__ float bf2f(unsigned short u) {
    return __uint_as_float(((unsigned)u) << 16);
}
__device__ __forceinline__ unsigned short f2bf(float f) {
    unsigned u = __float_as_uint(f);
    u += 0x7fffu + ((u >> 16) & 1u);   // RNE
    return (unsigned short)(u >> 16);
}

__device__ __forceinline__ void gl_lds16(const void* g, void* l) {
    __builtin_amdgcn_global_load_lds(
        (const __attribute__((address_space(1))) unsigned int*)g,
        (__attribute__((address_space(3))) unsigned int*)l, 16, 0, 0);
}

__device__ __forceinline__ float wave_max(float v) {
    #pragma unroll
    for (int m = 1; m < 64; m <<= 1) v = fmaxf(v, __shfl_xor(v, m, 64));
    return v;
}
__device__ __forceinline__ float wave_sum(float v) {
    #pragma unroll
    for (int m = 1; m < 64; m <<= 1) v += __shfl_xor(v, m, 64);
    return v;
}

// ---- prep: W1 f32 (4096x128) -> transposed bf16 hi/lo splits (128x4096) ----
__global__ void k_prep(const float* __restrict__ w1,
                       unsigned short* __restrict__ w1h,
                       unsigned short* __restrict__ w1l) {
    int tid = blockIdx.x * 256 + threadIdx.x;     // 524288 total
    int n = tid >> 12, k = tid & 4095;
    float v = w1[k * 128 + n];
    unsigned short hi = f2bf(v);
    w1h[tid] = hi;
    w1l[tid] = f2bf(v - bf2f(hi));
}

// ---- GEMM1: h = relu(x @ W1 + b1), split-bf16 3-pass MFMA, f32 in/out -----
// (unchanged from R2 — isolate the logits-stage variable)
__global__ __launch_bounds__(256) void k_gemm(const float* __restrict__ x,
                                              const unsigned short* __restrict__ w1h,
                                              const unsigned short* __restrict__ w1l,
                                              const float* __restrict__ b1,
                                              float* __restrict__ hout) {
    __shared__ unsigned short sAh[2][32 * 64], sAl[2][32 * 64];
    __shared__ unsigned short sBh[2][128 * 64], sBl[2][128 * 64];
    const int t = threadIdx.x;
    const int w = t >> 6, lane = t & 63;
    const int l15 = lane & 15, l4 = lane >> 4;
    const int rowBase = blockIdx.x << 5;

    f32x4 acc[2][2];
    #pragma unroll
    for (int i = 0; i < 2; ++i)
        #pragma unroll
        for (int j = 0; j < 2; ++j) {
            f32x4 z = {0.f, 0.f, 0.f, 0.f};
            acc[i][j] = z;
        }

    const int am = t >> 3, as = t & 7;
    const int apc = as ^ (am & 7);

    auto stage = [&](int buf, int k0) {
        #pragma unroll
        for (int j = 0; j < 4; ++j) {
            int c = j * 256 + t;
            int n = c >> 3;
            int cl = (c & 7) ^ (n & 7);
            const size_t go = (size_t)n * 4096 + k0 + (cl << 3);
            gl_lds16(w1h + go, &sBh[buf][c << 3]);
            gl_lds16(w1l + go, &sBl[buf][c << 3]);
        }
        const float* src = x + ((size_t)(rowBase + am) << 12) + k0 + (as << 3);
        float4 a0 = *(const float4*)src;
        float4 a1 = *(const float4*)(src + 4);
        float av[8] = {a0.x, a0.y, a0.z, a0.w, a1.x, a1.y, a1.z, a1.w};
        short8 H, L;
        #pragma unroll
        for (int i = 0; i < 8; ++i) {
            unsigned short hi = f2bf(av[i]);
            H[i] = (short)hi;
            L[i] = (short)f2bf(av[i] - bf2f(hi));
        }
        *(short8*)&sAh[buf][((am << 3) + apc) << 3] = H;
        *(short8*)&sAl[buf][((am << 3) + apc) << 3] = L;
    };

    stage(0, 0);
    __syncthreads();
    for (int it = 0; it < 64; ++it) {
        int buf = it & 1;
        if (it + 1 < 64) stage(buf ^ 1, (it + 1) << 6);
        #pragma unroll
        for (int ks = 0; ks < 2; ++ks) {
            short8 ah[2], al[2], bh[2], bl[2];
            #pragma unroll
            for (int mf = 0; mf < 2; ++mf) {
                int rm = (mf << 4) + l15;
                int pc = ((ks << 2) + l4) ^ (rm & 7);
                ah[mf] = *(const short8*)&sAh[buf][(((rm << 3) + pc)) << 3];
                al[mf] = *(const short8*)&sAl[buf][(((rm << 3) + pc)) << 3];
            }
            #pragma unroll
            for (int nf = 0; nf < 2; ++nf) {
                int rn = (w << 5) + (nf << 4) + l15;
                int pc = ((ks << 2) + l4) ^ (rn & 7);
                bh[nf] = *(const short8*)&sBh[buf][(((rn << 3) + pc)) << 3];
                bl[nf] = *(const short8*)&sBl[buf][(((rn << 3) + pc)) << 3];
            }
            #pragma unroll
            for (int mf = 0; mf < 2; ++mf)
                #pragma unroll
                for (int nf = 0; nf < 2; ++nf) {
                    acc[mf][nf] = __builtin_amdgcn_mfma_f32_16x16x32_bf16(
                        ah[mf], bh[nf], acc[mf][nf], 0, 0, 0);
                    acc[mf][nf] = __builtin_amdgcn_mfma_f32_16x16x32_bf16(
                        ah[mf], bl[nf], acc[mf][nf], 0, 0, 0);
                    acc[mf][nf] = __builtin_amdgcn_mfma_f32_16x16x32_bf16(
                        al[mf], bh[nf], acc[mf][nf], 0, 0, 0);
                }
        }
        __syncthreads();
    }

    #pragma unroll
    for (int nf = 0; nf < 2; ++nf) {
        int col = (w << 5) + (nf << 4) + l15;
        float bias = b1[col];
        #pragma unroll
        for (int mf = 0; mf < 2; ++mf) {
            int r0 = rowBase + (mf << 4) + (l4 << 2);
            #pragma unroll
            for (int rr = 0; rr < 4; ++rr) {
                float v = acc[mf][nf][rr] + bias;
                hout[(size_t)(r0 + rr) * 128 + col] = v > 0.f ? v : 0.f;
            }
        }
    }
}

// ---- fused logits+stats: 32 rows/block, thread=(row, 8-expert group) ------
// All W2/h/m1 operands are VGPR float4 loads (L1 broadcast across redundant
// lanes) — no scalar-load or LDS-operand-stream dependence. lg lives in LDS.
__global__ __launch_bounds__(256) void k_logstats(const float* __restrict__ h,
                                                  const float* __restrict__ w2,
                                                  const float* __restrict__ b2,
                                                  const float* __restrict__ m1,
                                                  const float* __restrict__ m2,
                                                  float* __restrict__ out) {
    __shared__ float lgs[5 * 32 * 64];   // 40 KB
    const int t = threadIdx.x;
    const int lr = t >> 3;               // local row 0..31
    const int eg = t & 7;                // expert group
    const int e0 = eg << 3;
    const int rowBase = blockIdx.x << 5;
    const int row = rowBase + lr;

    float acc[5][8];
    #pragma unroll
    for (int s = 0; s < 5; ++s)
        #pragma unroll
        for (int e = 0; e < 8; ++e) acc[s][e] = 0.f;

    const float* hp = h + (size_t)row * 128;
    const size_t m1row = (size_t)row * 128;

    for (int k = 0; k < 128; k += 4) {
        float4 h4 = *(const float4*)(hp + k);
        float hv[4] = {h4.x, h4.y, h4.z, h4.w};
        float w2v[4][8];
        #pragma unroll
        for (int kk = 0; kk < 4; ++kk) {
            float4 wa = *(const float4*)(w2 + (k + kk) * 64 + e0);
            float4 wb = *(const float4*)(w2 + (k + kk) * 64 + e0 + 4);
            w2v[kk][0] = wa.x; w2v[kk][1] = wa.y; w2v[kk][2] = wa.z; w2v[kk][3] = wa.w;
            w2v[kk][4] = wb.x; w2v[kk][5] = wb.y; w2v[kk][6] = wb.z; w2v[kk][7] = wb.w;
        }
        #pragma unroll
        for (int s = 0; s < 5; ++s) {
            float4 mu = *(const float4*)(m1 + (size_t)s * B_ROWS * 128 + m1row + k);
            float hd[4];
            hd[0] = (mu.x >= 0.3f) ? hv[0] * SCALE : 0.f;
            hd[1] = (mu.y >= 0.3f) ? hv[1] * SCALE : 0.f;
            hd[2] = (mu.z >= 0.3f) ? hv[2] * SCALE : 0.f;
            hd[3] = (mu.w >= 0.3f) ? hv[3] * SCALE : 0.f;
            #pragma unroll
            for (int kk = 0; kk < 4; ++kk)        // k ascending: same order as R2
                #pragma unroll
                for (int e = 0; e < 8; ++e)
                    acc[s][e] += hd[kk] * w2v[kk][e];
        }
    }

    // epilogue: +b2, mask2*scale, park in LDS
    float4 ba = *(const float4*)(b2 + e0);
    float4 bb = *(const float4*)(b2 + e0 + 4);
    float bv[8] = {ba.x, ba.y, ba.z, ba.w, bb.x, bb.y, bb.z, bb.w};
    #pragma unroll
    for (int s = 0; s < 5; ++s) {
        const float* m2p = m2 + ((size_t)s * B_ROWS + row) * 64 + e0;
        float4 ma = *(const float4*)m2p;
        float4 mb = *(const float4*)(m2p + 4);
        float mk[8] = {ma.x, ma.y, ma.z, ma.w, mb.x, mb.y, mb.z, mb.w};
        float lv[8];
        #pragma unroll
        for (int e = 0; e < 8; ++e) {
            float v = acc[s][e] + bv[e];
            lv[e] = (mk[e] >= 0.3f) ? v * SCALE : 0.f;
        }
        float* dst = &lgs[((s << 5) + lr) * 64 + e0];
        *(float4*)dst = make_float4(lv[0], lv[1], lv[2], lv[3]);
        *(float4*)(dst + 4) = make_float4(lv[4], lv[5], lv[6], lv[7]);
    }
    __syncthreads();

    // ---- stats phase: wave per 8 rows, lane = expert (math identical R2) ---
    const int wv = t >> 6, lane = t & 63;
    for (int r8 = 0; r8 < 8; ++r8) {
        int r = (wv << 3) + r8;          // local row
        float l[5], p[5];
        #pragma unroll
        for (int s = 0; s < 5; ++s)
            l[s] = lgs[((s << 5) + r) * 64 + lane];

        float ml = ((((l[0] + l[1]) + l[2]) + l[3]) + l[4]) / 5.0f;

        #pragma unroll
        for (int s = 0; s < 5; ++s) {
            float mx = wave_max(l[s]);
            float ev = expf(l[s] - mx);
            float sm = wave_sum(ev);
            p[s] = ev / sm;
        }

        float mx = wave_max(ml);
        float ev = expf(ml - mx);
        float sm = wave_sum(ev);
        float prob = ev / sm;

        float mean = ((((p[0] + p[1]) + p[2]) + p[3]) + p[4]) / 5.0f;
        float var = 0.f;
        #pragma unroll
        for (int s = 0; s < 5; ++s) { float d = p[s] - mean; var += d * d; }
        float sd = sqrtf(var * 0.25f);
        float unc = wave_sum(sd) / 64.0f;

        float pv = prob;
        float vv[4]; int vi[4];
        #pragma unroll
        for (int t4 = 0; t4 < 4; ++t4) {
            float bvx = pv; int bi = lane;
            #pragma unroll
            for (int m = 1; m < 64; m <<= 1) {
                float ov = __shfl_xor(bvx, m, 64);
                int oi = __shfl_xor(bi, m, 64);
                if (ov > bvx || (ov == bvx && oi < bi)) { bvx = ov; bi = oi; }
            }
            vv[t4] = bvx; vi[t4] = bi;
            if (lane == bi) pv = -1.f;
        }

        if (lane == 0) {
            int grow = rowBase + r;
            bool ug = unc > 0.3f;
            float4 fi = make_float4((float)vi[0], (float)vi[1],
                                    ug ? (float)vi[2] : -1.f,
                                    ug ? (float)vi[3] : -1.f);
            *(float4*)(out + (size_t)grow * 4) = fi;
            float4 fp = make_float4(vv[0], vv[1],
                                    ug ? vv[2] : 0.f,
                                    ug ? vv[3] : 0.f);
            *(float4*)(out + 65536 + (size_t)grow * 4) = fp;
            out[131072 + grow] = unc;
        }
    }
}

extern "C" void kernel_launch(void* const* d_in, const int* in_sizes, int n_in,
                              void* d_out, int out_size, void* d_ws, size_t ws_size,
                              hipStream_t stream) {
    const float* x  = (const float*)d_in[0];
    const float* W1 = (const float*)d_in[1];
    const float* b1 = (const float*)d_in[2];
    const float* W2 = (const float*)d_in[3];
    const float* b2 = (const float*)d_in[4];
    const float* m1 = (const float*)d_in[5];
    const float* m2 = (const float*)d_in[6];
    float* out = (float*)d_out;
    char* ws = (char*)d_ws;

    unsigned short* w1h = (unsigned short*)ws;                // 1 MB
    unsigned short* w1l = (unsigned short*)(ws + (1 << 20));  // 1 MB
    float* h = (float*)(ws + (2 << 20));                      // 8 MB

    k_prep    <<<2048, 256, 0, stream>>>(W1, w1h, w1l);
    k_gemm    <<<512,  256, 0, stream>>>(x, w1h, w1l, b1, h);
    k_logstats<<<512,  256, 0, stream>>>(h, W2, b2, m1, m2, out);
}